// Round 10
// baseline (94.542 us; speedup 1.0000x reference)
//
#include <hip/hip_runtime.h>
#include <hip/hip_bf16.h>
#include <math.h>
#include <stdint.h>

#define NT 256
constexpr int Hc = 1024, BOTc = 128, RDc = 48, Nc = 4096;
constexpr int ROWS = 8192;          // B*S
constexpr float INV_SQRT_RD = 0.14433756729740643f;  // 1/sqrt(48)

typedef short bf16x8 __attribute__((ext_vector_type(8)));
typedef float f32x4 __attribute__((ext_vector_type(4)));

// ---------- small helpers ----------
__device__ __forceinline__ uint32_t umin32(uint32_t a, uint32_t b) { return a < b ? a : b; }
__device__ __forceinline__ uint32_t umax32(uint32_t a, uint32_t b) { return a > b ? a : b; }
__device__ __forceinline__ void ce_asc(uint32_t& x, uint32_t& y) {
  uint32_t lo = umin32(x, y), hi = umax32(x, y); x = lo; y = hi;
}
__device__ __forceinline__ uint32_t pack_score(float s, int slot) {
  uint32_t u = __float_as_uint(s);
  u = (u & 0x80000000u) ? ~u : (u | 0x80000000u);
  return (u & 0xFFFFF000u) | (uint32_t)slot;
}
__device__ __forceinline__ float unpack_score(uint32_t p) {
  uint32_t m = p & 0xFFFFF000u;
  uint32_t f = (m & 0x80000000u) ? (m ^ 0x80000000u) : ~m;
  return __uint_as_float(f);
}
__device__ __forceinline__ void merge_top8(uint32_t a[8], const uint32_t b[8]) {
  uint32_t m[8];
#pragma unroll
  for (int i = 0; i < 8; ++i) m[i] = umax32(a[i], b[7 - i]);
  ce_asc(m[0], m[4]); ce_asc(m[1], m[5]); ce_asc(m[2], m[6]); ce_asc(m[3], m[7]);
  ce_asc(m[0], m[2]); ce_asc(m[1], m[3]); ce_asc(m[4], m[6]); ce_asc(m[5], m[7]);
  ce_asc(m[0], m[1]); ce_asc(m[2], m[3]); ce_asc(m[4], m[5]); ce_asc(m[6], m[7]);
#pragma unroll
  for (int i = 0; i < 8; ++i) a[i] = m[i];
}
__device__ __forceinline__ void top8_insert(uint32_t top[8], uint32_t p) {
  if (p > top[0]) {
    top[0] = p;
    ce_asc(top[0], top[1]); ce_asc(top[1], top[2]); ce_asc(top[2], top[3]);
    ce_asc(top[3], top[4]); ce_asc(top[4], top[5]); ce_asc(top[5], top[6]);
    ce_asc(top[6], top[7]);
  }
}
__device__ __forceinline__ uint16_t bf16bits(float x) {      // RNE
  uint32_t u = __float_as_uint(x);
  return (uint16_t)(((u + 0x7FFFu + ((u >> 16) & 1u)) >> 16) & 0xFFFFu);
}
__device__ __forceinline__ float bf2f(uint16_t h) {
  return __uint_as_float((uint32_t)h << 16);
}

// ---------- prep: only what k_xw/k_scores need (avb cvt moved into k_xw launch) ----------
// [0,64) w48 ; [64,832) rk ; [832,1856) hb ; [1856,1888) cvt w1
constexpr int GP_W48 = 64, GP_RK = 768, GP_HB = 1024, GP_CVW = 32;
__global__ __launch_bounds__(256) void k_prep_all(
    const float* __restrict__ hidden, const float* __restrict__ q_proj_w,
    const float* __restrict__ router_w, const float* __restrict__ aux_keys,
    const float* __restrict__ rel, const float* __restrict__ unc_w1,
    uint16_t* __restrict__ xb, float* __restrict__ log_var,
    uint16_t* __restrict__ wcat, uint16_t* __restrict__ rk_b) {
  int bid = blockIdx.x;
  int tid = threadIdx.x;
  if (bid < GP_W48) {
    __shared__ float rw[BOTc];
    int j = bid;
    if (j >= RDc) {
      for (int hh = tid; hh < Hc; hh += NT) wcat[(size_t)(256 + j) * Hc + hh] = 0;
      return;
    }
    for (int d = tid; d < BOTc; d += NT) rw[d] = router_w[j * BOTc + d];
    __syncthreads();
    float acc[4] = {0.f, 0.f, 0.f, 0.f};
#pragma unroll 4
    for (int d = 0; d < BOTc; ++d) {
      float r = rw[d];
#pragma unroll
      for (int jj = 0; jj < 4; ++jj)
        acc[jj] = fmaf(r, q_proj_w[d * Hc + tid + 256 * jj], acc[jj]);
    }
#pragma unroll
    for (int jj = 0; jj < 4; ++jj)
      wcat[(size_t)(256 + j) * Hc + tid + 256 * jj] = bf16bits(acc[jj]);
    return;
  }
  bid -= GP_W48;
  if (bid < GP_RK) {
    int gid = bid * NT + tid;
    int n = gid / RDc, r = gid - n * RDc;
    float acc = 0.f;
#pragma unroll 8
    for (int d = 0; d < BOTc; ++d)
      acc = fmaf(aux_keys[n * BOTc + d], router_w[r * BOTc + d], acc);
    rk_b[(size_t)n * 64 + r] = bf16bits(acc * INV_SQRT_RD);
    if (r < 16) rk_b[(size_t)n * 64 + 48 + r] = (r == 0) ? bf16bits(rel[n]) : (uint16_t)0;
    return;
  }
  bid -= GP_RK;
  if (bid < GP_HB) {
    int wave = tid >> 6, lane = tid & 63;
    int row = bid * 8 + wave * 2;
    const float4* r0 = reinterpret_cast<const float4*>(hidden + (size_t)row * Hc);
    const float4* r1 = reinterpret_cast<const float4*>(hidden + (size_t)(row + 1) * Hc);
    float4 v0[4], v1[4];
#pragma unroll
    for (int i = 0; i < 4; ++i) v0[i] = r0[lane + 64 * i];
#pragma unroll
    for (int i = 0; i < 4; ++i) v1[i] = r1[lane + 64 * i];
    float s0 = 0.f, q0 = 0.f, s1 = 0.f, q1 = 0.f;
#pragma unroll
    for (int i = 0; i < 4; ++i) {
      ushort4 h;
      h.x = bf16bits(v0[i].x); h.y = bf16bits(v0[i].y);
      h.z = bf16bits(v0[i].z); h.w = bf16bits(v0[i].w);
      *reinterpret_cast<ushort4*>(xb + (size_t)row * Hc + (lane + 64 * i) * 4) = h;
      s0 += v0[i].x + v0[i].y + v0[i].z + v0[i].w;
      q0 += v0[i].x * v0[i].x + v0[i].y * v0[i].y + v0[i].z * v0[i].z + v0[i].w * v0[i].w;
    }
#pragma unroll
    for (int i = 0; i < 4; ++i) {
      ushort4 h;
      h.x = bf16bits(v1[i].x); h.y = bf16bits(v1[i].y);
      h.z = bf16bits(v1[i].z); h.w = bf16bits(v1[i].w);
      *reinterpret_cast<ushort4*>(xb + (size_t)(row + 1) * Hc + (lane + 64 * i) * 4) = h;
      s1 += v1[i].x + v1[i].y + v1[i].z + v1[i].w;
      q1 += v1[i].x * v1[i].x + v1[i].y * v1[i].y + v1[i].z * v1[i].z + v1[i].w * v1[i].w;
    }
#pragma unroll
    for (int d = 32; d >= 1; d >>= 1) {
      s0 += __shfl_down(s0, d); q0 += __shfl_down(q0, d);
      s1 += __shfl_down(s1, d); q1 += __shfl_down(q1, d);
    }
    if (lane == 0) {
      float m0 = s0 * (1.f / Hc), m1 = s1 * (1.f / Hc);
      log_var[row]     = log1pf(q0 * (1.f / Hc) - m0 * m0);
      log_var[row + 1] = log1pf(q1 * (1.f / Hc) - m1 * m1);
    }
    return;
  }
  bid -= GP_HB;
  {
    // unc_w1 -> wcat rows 0-255
    float4 v[8];
    int base = bid * 2048 + tid;
#pragma unroll
    for (int i = 0; i < 8; ++i) v[i] = reinterpret_cast<const float4*>(unc_w1)[base + i * 256];
#pragma unroll
    for (int i = 0; i < 8; ++i) {
      ushort4 h;
      h.x = bf16bits(v[i].x); h.y = bf16bits(v[i].y);
      h.z = bf16bits(v[i].z); h.w = bf16bits(v[i].w);
      reinterpret_cast<ushort4*>(wcat)[base + i * 256] = h;
    }
  }
}

// ---------- fused rq + uncertainty GEMM (+redsum, +avb cvt co-scheduled) ----------
// blocks 0-639: GEMM (8x80 XCD-bijective). block 640: redsum.
// blocks 641-1152: aux_values fp32->bf16 (consumed only by k_final; overlaps GEMM).
__global__ __launch_bounds__(256) void k_xw(const uint16_t* __restrict__ xb,
                                            const uint16_t* __restrict__ wcat,
                                            const float* __restrict__ aux_values,
                                            const float* __restrict__ b1,
                                            const float* __restrict__ w2,
                                            const float* __restrict__ log_var,
                                            float* __restrict__ stats,
                                            float* __restrict__ uncp,
                                            uint16_t* __restrict__ rq_b,
                                            uint16_t* __restrict__ avb) {
  int bid = blockIdx.x;
  int tid = threadIdx.x;
  if (bid == 640) {                                  // folded redsum
    float s = 0.f;
    for (int i = tid; i < ROWS; i += NT) s += log_var[i];
#pragma unroll
    for (int d = 32; d >= 1; d >>= 1) s += __shfl_down(s, d);
    __shared__ float ls[4];
    int lane = tid & 63, wv = tid >> 6;
    if (lane == 0) ls[wv] = s;
    __syncthreads();
    if (tid == 0) {
      s = ls[0] + ls[1] + ls[2] + ls[3];
      stats[0] = 1.f / (s * (1.f / ROWS) + 1e-6f);
    }
    return;
  }
  if (bid > 640) {                                   // avb cvt (BW work under GEMM)
    float4 v[8];
    int base = (bid - 641) * 2048 + tid;
#pragma unroll
    for (int i = 0; i < 8; ++i) v[i] = reinterpret_cast<const float4*>(aux_values)[base + i * 256];
#pragma unroll
    for (int i = 0; i < 8; ++i) {
      ushort4 h;
      h.x = bf16bits(v[i].x); h.y = bf16bits(v[i].y);
      h.z = bf16bits(v[i].z); h.w = bf16bits(v[i].w);
      reinterpret_cast<ushort4*>(avb)[base + i * 256] = h;
    }
    return;
  }
  __shared__ uint16_t As[2][64 * 72];
  __shared__ uint16_t Bs[2][64 * 72];
  int wid = (bid & 7) * 80 + (bid >> 3);             // XCD-contiguous (640 = 8*80)
  int rowg = wid / 5, colg = wid - rowg * 5;
  int wave = tid >> 6, lane = tid & 63;
  int l15 = lane & 15, lg = lane >> 4;
  int wr = wave >> 1, wc = wave & 1;
  int row0 = rowg * 64, n0 = colg * 64;
  int srow = tid >> 3, sseg = tid & 7;
  const uint16_t* agp = xb + (size_t)(row0 + srow) * Hc + sseg * 8;
  const uint16_t* bgp = wcat + (size_t)(n0 + srow) * Hc + sseg * 8;
  int sboff = srow * 72 + sseg * 8;
  int arow = wr * 32 + l15, brow = wc * 32 + l15;

  bf16x8 a0A = *reinterpret_cast<const bf16x8*>(agp);
  bf16x8 a1A = *reinterpret_cast<const bf16x8*>(agp + (size_t)32 * Hc);
  bf16x8 b0A = *reinterpret_cast<const bf16x8*>(bgp);
  bf16x8 b1A = *reinterpret_cast<const bf16x8*>(bgp + (size_t)32 * Hc);
  bf16x8 a0B = *reinterpret_cast<const bf16x8*>(agp + 64);
  bf16x8 a1B = *reinterpret_cast<const bf16x8*>(agp + (size_t)32 * Hc + 64);
  bf16x8 b0B = *reinterpret_cast<const bf16x8*>(bgp + 64);
  bf16x8 b1B = *reinterpret_cast<const bf16x8*>(bgp + (size_t)32 * Hc + 64);
  f32x4 acc00 = {0.f,0.f,0.f,0.f}, acc01 = {0.f,0.f,0.f,0.f};
  f32x4 acc10 = {0.f,0.f,0.f,0.f}, acc11 = {0.f,0.f,0.f,0.f};

  for (int tt = 0; tt < 16; tt += 2) {
    *reinterpret_cast<bf16x8*>(&As[0][sboff]) = a0A;
    *reinterpret_cast<bf16x8*>(&As[0][sboff + 32 * 72]) = a1A;
    *reinterpret_cast<bf16x8*>(&Bs[0][sboff]) = b0A;
    *reinterpret_cast<bf16x8*>(&Bs[0][sboff + 32 * 72]) = b1A;
    if (tt + 2 < 16) {
      int k0 = (tt + 2) * 64;
      a0A = *reinterpret_cast<const bf16x8*>(agp + k0);
      a1A = *reinterpret_cast<const bf16x8*>(agp + (size_t)32 * Hc + k0);
      b0A = *reinterpret_cast<const bf16x8*>(bgp + k0);
      b1A = *reinterpret_cast<const bf16x8*>(bgp + (size_t)32 * Hc + k0);
    }
    __syncthreads();
#pragma unroll
    for (int ks = 0; ks < 2; ++ks) {
      bf16x8 a0 = *reinterpret_cast<const bf16x8*>(&As[0][arow * 72 + ks * 32 + lg * 8]);
      bf16x8 a1 = *reinterpret_cast<const bf16x8*>(&As[0][(arow + 16) * 72 + ks * 32 + lg * 8]);
      bf16x8 b0 = *reinterpret_cast<const bf16x8*>(&Bs[0][brow * 72 + ks * 32 + lg * 8]);
      bf16x8 b1f = *reinterpret_cast<const bf16x8*>(&Bs[0][(brow + 16) * 72 + ks * 32 + lg * 8]);
      acc00 = __builtin_amdgcn_mfma_f32_16x16x32_bf16(a0, b0, acc00, 0, 0, 0);
      acc01 = __builtin_amdgcn_mfma_f32_16x16x32_bf16(a0, b1f, acc01, 0, 0, 0);
      acc10 = __builtin_amdgcn_mfma_f32_16x16x32_bf16(a1, b0, acc10, 0, 0, 0);
      acc11 = __builtin_amdgcn_mfma_f32_16x16x32_bf16(a1, b1f, acc11, 0, 0, 0);
    }
    *reinterpret_cast<bf16x8*>(&As[1][sboff]) = a0B;
    *reinterpret_cast<bf16x8*>(&As[1][sboff + 32 * 72]) = a1B;
    *reinterpret_cast<bf16x8*>(&Bs[1][sboff]) = b0B;
    *reinterpret_cast<bf16x8*>(&Bs[1][sboff + 32 * 72]) = b1B;
    if (tt + 3 < 16) {
      int k0 = (tt + 3) * 64;
      a0B = *reinterpret_cast<const bf16x8*>(agp + k0);
      a1B = *reinterpret_cast<const bf16x8*>(agp + (size_t)32 * Hc + k0);
      b0B = *reinterpret_cast<const bf16x8*>(bgp + k0);
      b1B = *reinterpret_cast<const bf16x8*>(bgp + (size_t)32 * Hc + k0);
    }
    __syncthreads();
#pragma unroll
    for (int ks = 0; ks < 2; ++ks) {
      bf16x8 a0 = *reinterpret_cast<const bf16x8*>(&As[1][arow * 72 + ks * 32 + lg * 8]);
      bf16x8 a1 = *reinterpret_cast<const bf16x8*>(&As[1][(arow + 16) * 72 + ks * 32 + lg * 8]);
      bf16x8 b0 = *reinterpret_cast<const bf16x8*>(&Bs[1][brow * 72 + ks * 32 + lg * 8]);
      bf16x8 b1f = *reinterpret_cast<const bf16x8*>(&Bs[1][(brow + 16) * 72 + ks * 32 + lg * 8]);
      acc00 = __builtin_amdgcn_mfma_f32_16x16x32_bf16(a0, b0, acc00, 0, 0, 0);
      acc01 = __builtin_amdgcn_mfma_f32_16x16x32_bf16(a0, b1f, acc01, 0, 0, 0);
      acc10 = __builtin_amdgcn_mfma_f32_16x16x32_bf16(a1, b0, acc10, 0, 0, 0);
      acc11 = __builtin_amdgcn_mfma_f32_16x16x32_bf16(a1, b1f, acc11, 0, 0, 0);
    }
  }
  if (colg < 4) {
    int gc0 = n0 + wc * 32 + l15;
    float b1v0 = b1[gc0],      w2v0 = w2[gc0];
    float b1v1 = b1[gc0 + 16], w2v1 = w2[gc0 + 16];
    int strip = colg * 2 + wc;
    float part0[4], part1[4];
#pragma unroll
    for (int r = 0; r < 4; ++r) {
      float x00 = acc00[r] + b1v0, x01 = acc01[r] + b1v1;
      float x10 = acc10[r] + b1v0, x11 = acc11[r] + b1v1;
      float g00 = 0.5f * x00 * (1.f + erff(x00 * 0.70710678118654752f));
      float g01 = 0.5f * x01 * (1.f + erff(x01 * 0.70710678118654752f));
      float g10 = 0.5f * x10 * (1.f + erff(x10 * 0.70710678118654752f));
      float g11 = 0.5f * x11 * (1.f + erff(x11 * 0.70710678118654752f));
      part0[r] = fmaf(g00, w2v0, g01 * w2v1);
      part1[r] = fmaf(g10, w2v0, g11 * w2v1);
    }
#pragma unroll
    for (int d = 1; d < 16; d <<= 1)
#pragma unroll
      for (int r = 0; r < 4; ++r) {
        part0[r] += __shfl_xor(part0[r], d);
        part1[r] += __shfl_xor(part1[r], d);
      }
    if (l15 == 0) {
#pragma unroll
      for (int r = 0; r < 4; ++r) {
        uncp[(size_t)(row0 + wr * 32 + lg * 4 + r) * 8 + strip] = part0[r];
        uncp[(size_t)(row0 + wr * 32 + 16 + lg * 4 + r) * 8 + strip] = part1[r];
      }
    }
  } else {
    int colA = wc * 32 + l15, colB = colA + 16;
#pragma unroll
    for (int r = 0; r < 4; ++r) {
      int rA = row0 + wr * 32 + lg * 4 + r, rB = rA + 16;
      uint16_t vA = bf16bits(acc00[r]);
      uint16_t vB = (colB == 48) ? (uint16_t)0x3F80u : bf16bits(acc01[r]);
      uint16_t uA = bf16bits(acc10[r]);
      uint16_t uB = (colB == 48) ? (uint16_t)0x3F80u : bf16bits(acc11[r]);
      rq_b[(size_t)rA * 64 + colA] = vA;
      rq_b[(size_t)rA * 64 + colB] = vB;
      rq_b[(size_t)rB * 64 + colA] = uA;
      rq_b[(size_t)rB * 64 + colB] = uB;
    }
  }
}

// ---------- scores via MFMA (swapped operands) + in-register top-8, reg-prefetch ----------
__global__ __launch_bounds__(256) void k_scores_mfma(const uint16_t* __restrict__ rq_b,
                                                     const uint16_t* __restrict__ rk_b,
                                                     uint32_t* __restrict__ cand) {
  int tid = threadIdx.x;
  int wave = tid >> 6, lane = tid & 63;
  int l15 = lane & 15, lg = lane >> 4;
  int rowg = blockIdx.x >> 3, range = blockIdx.x & 7;
  int q0 = rowg * 64 + wave * 16;
  const uint16_t* qp = rq_b + (size_t)(q0 + l15) * 64 + lg * 8;
  bf16x8 qf1 = *reinterpret_cast<const bf16x8*>(qp);
  bf16x8 qf2 = *reinterpret_cast<const bf16x8*>(qp + 32);
  uint32_t top[8];
#pragma unroll
  for (int q = 0; q < 8; ++q) top[q] = 0u;
  int sbase = range * 512;
  const uint16_t* kp = rk_b + (size_t)(sbase + l15) * 64 + lg * 8;
  bf16x8 a1c = *reinterpret_cast<const bf16x8*>(kp);
  bf16x8 a2c = *reinterpret_cast<const bf16x8*>(kp + 32);
  bf16x8 a3c = *reinterpret_cast<const bf16x8*>(kp + 1024);
  bf16x8 a4c = *reinterpret_cast<const bf16x8*>(kp + 1024 + 32);
#pragma unroll
  for (int t = 0; t < 32; t += 2) {
    bf16x8 a1n, a2n, a3n, a4n;
    if (t < 30) {
      const uint16_t* kpn = kp + (size_t)(t + 2) * 1024;
      a1n = *reinterpret_cast<const bf16x8*>(kpn);
      a2n = *reinterpret_cast<const bf16x8*>(kpn + 32);
      a3n = *reinterpret_cast<const bf16x8*>(kpn + 1024);
      a4n = *reinterpret_cast<const bf16x8*>(kpn + 1024 + 32);
    }
    int s0 = sbase + t * 16;
    f32x4 acc0 = {0.f,0.f,0.f,0.f}, acc1 = {0.f,0.f,0.f,0.f};
    acc0 = __builtin_amdgcn_mfma_f32_16x16x32_bf16(a1c, qf1, acc0, 0, 0, 0);
    acc1 = __builtin_amdgcn_mfma_f32_16x16x32_bf16(a3c, qf1, acc1, 0, 0, 0);
    acc0 = __builtin_amdgcn_mfma_f32_16x16x32_bf16(a2c, qf2, acc0, 0, 0, 0);
    acc1 = __builtin_amdgcn_mfma_f32_16x16x32_bf16(a4c, qf2, acc1, 0, 0, 0);
#pragma unroll
    for (int r = 0; r < 4; ++r) top8_insert(top, pack_score(acc0[r], s0 + lg * 4 + r));
#pragma unroll
    for (int r = 0; r < 4; ++r) top8_insert(top, pack_score(acc1[r], s0 + 16 + lg * 4 + r));
    if (t < 30) { a1c = a1n; a2c = a2n; a3c = a3n; a4c = a4n; }
  }
#pragma unroll
  for (int dd = 16; dd <= 32; dd <<= 1) {
    uint32_t o[8];
#pragma unroll
    for (int q = 0; q < 8; ++q) o[q] = __shfl_xor(top[q], dd);
    merge_top8(top, o);
  }
  if (lg == 0) {
    int row = q0 + l15;
#pragma unroll
    for (int q = 0; q < 8; ++q) cand[((size_t)row * 8 + range) * 8 + q] = top[q];
  }
}

// ---------- merge + softmax + gate + gather + output: 4 rows per block ----------
__global__ __launch_bounds__(256) void k_final(const uint16_t* __restrict__ xb,
                                               const uint16_t* __restrict__ avb,
                                               const uint32_t* __restrict__ cand,
                                               const float* __restrict__ log_var,
                                               const float* __restrict__ uncp,
                                               const float* __restrict__ stats,
                                               const float* __restrict__ b2,
                                               const float* __restrict__ gw,
                                               const float* __restrict__ gb,
                                               float* __restrict__ out) {
  int tid = threadIdx.x;
  int wave = tid >> 6, lane = tid & 63;
  int row0 = blockIdx.x * 4;
  __shared__ float ws_[4][8]; __shared__ int wi_[4][8]; __shared__ float sg[4];
  {
    int row = row0 + wave;
    uint32_t l[8];
    float up = 0.f;
    if (lane < 8) {
      const uint32_t* c = cand + (size_t)row * 64 + lane * 8;
#pragma unroll
      for (int q = 0; q < 8; ++q) l[q] = c[q];
      up = uncp[(size_t)row * 8 + lane];
    } else {
#pragma unroll
      for (int q = 0; q < 8; ++q) l[q] = 0u;
    }
#pragma unroll
    for (int d = 1; d < 8; d <<= 1) {
      uint32_t o[8];
#pragma unroll
      for (int q = 0; q < 8; ++q) o[q] = __shfl_xor(l[q], d);
      merge_top8(l, o);
      up += __shfl_xor(up, d);
    }
    if (lane == 0) {
      float sc[8];
#pragma unroll
      for (int q = 0; q < 8; ++q) sc[q] = unpack_score(l[q]);
      float mx = sc[7];
      float e[8]; float sum = 0.f;
#pragma unroll
      for (int q = 0; q < 8; ++q) { e[q] = expf(sc[q] - mx); sum += e[q]; }
      float inv = 1.f / sum;
#pragma unroll
      for (int q = 0; q < 8; ++q) { ws_[wave][q] = e[q] * inv; wi_[wave][q] = (int)(l[q] & 0xFFFu); }
      float learned = up + b2[0];
      float nv = log_var[row] * stats[0];
      float sig = 1.f / (1.f + expf(-learned));
      float u = nv * 0.5f + sig * 2.5f;
      u = fminf(fmaxf(u, 0.f), 5.f);
      sg[wave] = 1.f / (1.f + expf(-(gw[0] * u + gb[0])));
    }
  }
  __syncthreads();
  int h0 = tid * 4;
#pragma unroll
  for (int rr = 0; rr < 4; ++rr) {
    int row = row0 + rr;
    ushort4 hb = *reinterpret_cast<const ushort4*>(xb + (size_t)row * Hc + h0);
    float ax = 0.f, ay = 0.f, az = 0.f, aw = 0.f;
#pragma unroll
    for (int k = 0; k < 8; ++k) {
      float w = ws_[rr][k];
      ushort4 v = *reinterpret_cast<const ushort4*>(avb + (size_t)wi_[rr][k] * Hc + h0);
      ax = fmaf(w, bf2f(v.x), ax); ay = fmaf(w, bf2f(v.y), ay);
      az = fmaf(w, bf2f(v.z), az); aw = fmaf(w, bf2f(v.w), aw);
    }
    float g = sg[rr];
    float4 o;
    o.x = bf2f(hb.x) + g * ax; o.y = bf2f(hb.y) + g * ay;
    o.z = bf2f(hb.z) + g * az; o.w = bf2f(hb.w) + g * aw;
    *reinterpret_cast<float4*>(out + (size_t)row * Hc + h0) = o;
  }
}

extern "C" void kernel_launch(void* const* d_in, const int* in_sizes, int n_in,
                              void* d_out, int out_size, void* d_ws, size_t ws_size,
                              hipStream_t stream) {
  const float* hidden     = (const float*)d_in[0];
  const float* q_proj_w   = (const float*)d_in[1];
  const float* router_w   = (const float*)d_in[2];
  const float* aux_keys   = (const float*)d_in[3];
  const float* aux_values = (const float*)d_in[4];
  const float* rel        = (const float*)d_in[5];
  const float* unc_w1     = (const float*)d_in[6];
  const float* unc_b1     = (const float*)d_in[7];
  const float* unc_w2     = (const float*)d_in[8];
  const float* unc_b2     = (const float*)d_in[9];
  const float* gate_w1    = (const float*)d_in[10];
  const float* gate_bias  = (const float*)d_in[11];
  float* out = (float*)d_out;

  uint8_t* w = (uint8_t*)d_ws;              // ~28.5 MB used
  uint16_t* xb    = (uint16_t*)w;                 w += (size_t)ROWS * Hc * 2;     // 16 MB
  uint16_t* wcat  = (uint16_t*)w;                 w += (size_t)320 * Hc * 2;      // 640 KB
  uint16_t* avb   = (uint16_t*)w;                 w += (size_t)Nc * Hc * 2;       // 8 MB
  uint16_t* rq_b  = (uint16_t*)w;                 w += (size_t)ROWS * 64 * 2;     // 1 MB
  uint16_t* rk_b  = (uint16_t*)w;                 w += (size_t)Nc * 64 * 2;       // 512 KB
  float* log_var  = (float*)w;                    w += (size_t)ROWS * 4;
  float* uncp     = (float*)w;                    w += (size_t)ROWS * 8 * 4;      // 256 KB
  float* stats    = (float*)w;                    w += 256;
  uint32_t* cand  = (uint32_t*)w;                 w += (size_t)ROWS * 64 * 4;     // 2 MB

  k_prep_all<<<GP_W48 + GP_RK + GP_HB + GP_CVW, NT, 0, stream>>>(
      hidden, q_proj_w, router_w, aux_keys, rel, unc_w1,
      xb, log_var, wcat, rk_b);
  k_xw<<<1153, NT, 0, stream>>>(xb, wcat, aux_values, unc_b1, unc_w2, log_var,
                                stats, uncp, rq_b, avb);
  k_scores_mfma<<<1024, NT, 0, stream>>>(rq_b, rk_b, cand);
  k_final<<<ROWS / 4, NT, 0, stream>>>(xb, avb, cand, log_var, uncp,
                                       stats, unc_b2, gate_w1, gate_bias, out);
}